// Round 8
// baseline (4747.776 us; speedup 1.0000x reference)
//
#include <hip/hip_runtime.h>
#include <cstdint>
#include <cstddef>

#define SEQT  512
#define HID   1024
#define G3    3072

typedef __attribute__((ext_vector_type(8))) short bf16x8;
typedef __attribute__((ext_vector_type(8))) unsigned short u16x8;
typedef __attribute__((ext_vector_type(4))) float f32x4;

__device__ __forceinline__ float sigm(float x){ return 1.0f/(1.0f+expf(-x)); }
__device__ __forceinline__ float b2f(unsigned short s){ return __uint_as_float(((uint32_t)s)<<16); }
__device__ __forceinline__ unsigned short f2b(float f){
    uint32_t u=__float_as_uint(f);
    return (unsigned short)((u + 0x7FFFu + ((u>>16)&1u))>>16);
}

// ---------------------------------------------------------------------------
// MFMA GEMM (proven since R3). ASRC: 1=f32 reg-staged, 2=bf16 + (1+gate) fuse.
// BSRC: 1=f32 reg-staged. MODE: 0=f32+bias, 1=bf16 tanh(+bias+ctx).
// ---------------------------------------------------------------------------
template<int ASRC, int BSRC, int MODE>
__global__ __launch_bounds__(256) void mfma_gemm(
    const void* __restrict__ Av, const void* __restrict__ Bv,
    const float* __restrict__ bias, const float* __restrict__ ctx,
    const float* __restrict__ gate, void* __restrict__ Cv,
    int N, int K)
{
    __shared__ __align__(16) unsigned short As[128*64];
    __shared__ __align__(16) unsigned short Bs[128*64];
    const int tid = threadIdx.x;
    const int lane = tid & 63;
    const int w = tid >> 6;
    const int wm = w & 1, wn = w >> 1;
    const int m0 = blockIdx.y * 128, n0 = blockIdx.x * 128;

    f32x4 acc[4][4];
#pragma unroll
    for (int i = 0; i < 4; i++)
#pragma unroll
        for (int j = 0; j < 4; j++) acc[i][j] = (f32x4){0.f,0.f,0.f,0.f};

    for (int kt = 0; kt < K; kt += 64) {
        __syncthreads();
        if (ASRC == 1) {
            const float* Af = (const float*)Av;
#pragma unroll
            for (int p = 0; p < 4; p++) {
                const int q = p*256 + tid, row = q>>3, kc = q&7;
                const float* src = Af + (size_t)(m0+row)*K + kt + kc*8;
                float4 u = *(const float4*)src, v = *(const float4*)(src+4);
                __align__(16) unsigned short tmp[8] =
                    {f2b(u.x),f2b(u.y),f2b(u.z),f2b(u.w),f2b(v.x),f2b(v.y),f2b(v.z),f2b(v.w)};
                *(bf16x8*)&As[row*64 + kc*8] = *(const bf16x8*)tmp;
            }
        } else {
            const unsigned short* Ab = (const unsigned short*)Av;
#pragma unroll
            for (int p = 0; p < 4; p++) {
                const int q = p*256 + tid, row = q>>3, kc = q&7;
                const int b = (m0+row) >> 9;
                u16x8 hv = *(const u16x8*)(Ab + (size_t)(m0+row)*K + kt + kc*8);
                const float* gp = gate + (size_t)b*HID + kt + kc*8;
                float4 g0 = *(const float4*)gp, g1 = *(const float4*)(gp+4);
                const float gg[8] = {g0.x,g0.y,g0.z,g0.w,g1.x,g1.y,g1.z,g1.w};
                __align__(16) unsigned short tmp[8];
#pragma unroll
                for (int e = 0; e < 8; e++)
                    tmp[e] = f2b(b2f(hv[e]) * (1.0f + gg[e]));
                *(bf16x8*)&As[row*64 + kc*8] = *(const bf16x8*)tmp;
            }
        }
        {
            const float* Bf = (const float*)Bv;
#pragma unroll
            for (int p = 0; p < 4; p++) {
                const int q = p*256 + tid, row = q>>3, kc = q&7;
                const float* src = Bf + (size_t)(n0+row)*K + kt + kc*8;
                float4 u = *(const float4*)src, v = *(const float4*)(src+4);
                __align__(16) unsigned short tmp[8] =
                    {f2b(u.x),f2b(u.y),f2b(u.z),f2b(u.w),f2b(v.x),f2b(v.y),f2b(v.z),f2b(v.w)};
                *(bf16x8*)&Bs[row*64 + kc*8] = *(const bf16x8*)tmp;
            }
        }
        __syncthreads();
#pragma unroll
        for (int kg = 0; kg < 2; kg++) {
            bf16x8 af[4], bfr[4];
#pragma unroll
            for (int mi = 0; mi < 4; mi++)
                af[mi] = *(const bf16x8*)&As[(wm*64+mi*16+(lane&15))*64 + kg*32 + (lane>>4)*8];
#pragma unroll
            for (int ni = 0; ni < 4; ni++)
                bfr[ni] = *(const bf16x8*)&Bs[(wn*64+ni*16+(lane&15))*64 + kg*32 + (lane>>4)*8];
#pragma unroll
            for (int mi = 0; mi < 4; mi++)
#pragma unroll
                for (int ni = 0; ni < 4; ni++)
                    acc[mi][ni] = __builtin_amdgcn_mfma_f32_16x16x32_bf16(
                        af[mi], bfr[ni], acc[mi][ni], 0, 0, 0);
        }
    }

    const int cl = lane & 15, rg = lane >> 4;
    const int bct = m0 >> 9;
#pragma unroll
    for (int mi = 0; mi < 4; mi++) {
        const int rowb = m0 + wm*64 + mi*16 + rg*4;
#pragma unroll
        for (int ni = 0; ni < 4; ni++) {
            const int col = n0 + wn*64 + ni*16 + cl;
            const float bv = bias[col];
            const float cv = (MODE==1) ? ctx[(size_t)bct*HID + col] : 0.0f;
#pragma unroll
            for (int r = 0; r < 4; r++) {
                float val = acc[mi][ni][r] + bv;
                if (MODE==1) val = tanhf(val + cv);
                const size_t off = (size_t)(rowb+r)*N + col;
                if (MODE==0) ((float*)Cv)[off] = val;
                else ((unsigned short*)Cv)[off] = f2b(val);
            }
        }
    }
}

// ---------------------------------------------------------------------------
__global__ __launch_bounds__(256) void gate_kernel(
    const float* __restrict__ ctx, const float* __restrict__ Wg,
    const float* __restrict__ bg, float* __restrict__ gate)
{
    const int j = blockIdx.x * 256 + threadIdx.x;
    const int b = blockIdx.y;
    const float4* cp = (const float4*)(ctx + (size_t)b * HID);
    const float4* wp = (const float4*)(Wg + (size_t)j * HID);
    float acc = 0.0f;
#pragma unroll 4
    for (int k = 0; k < HID / 4; k++) {
        float4 c = cp[k], w = wp[k];
        acc += c.x * w.x + c.y * w.y + c.z * w.z + c.w * w.w;
    }
    gate[(size_t)b * HID + j] = sigm(acc + bg[j]);
}

// ---------------------------------------------------------------------------
// 4-stage pipelined GRU section (structure proven R7). This round:
//  * matvec: 32 pre-issued global h-loads pinned by sched_barrier(0) before
//    the 32 MFMAs -> deep VMEM pipeline (VGPR rises by design).
//  * wlds row-rotation swizzle: row k-layout rotated by (row&7)*8 shorts
//    (mod 1024) on write AND read -> uniform bank phases on ds_read_b128.
// ---------------------------------------------------------------------------
__device__ __forceinline__ void matvec32(const unsigned short* __restrict__ hrow,
                                         const unsigned short* __restrict__ wrowbase,
                                         int woff0, f32x4 (&A)[4])
{
    bf16x8 hb[32];
#pragma unroll
    for (int kg = 0; kg < 32; kg++)
        hb[kg] = *(const bf16x8*)(hrow + (size_t)kg*32);
    __builtin_amdgcn_sched_barrier(0);
#pragma unroll
    for (int kg = 0; kg < 32; kg++) {
        bf16x8 wv = *(const bf16x8*)(wrowbase + ((woff0 + kg*32) & 1023));
        A[kg & 3] = __builtin_amdgcn_mfma_f32_16x16x32_bf16(hb[kg], wv, A[kg & 3], 0,0,0);
    }
}

__global__ __launch_bounds__(384, 1) void gru_pipe(
    const float* __restrict__ Wih0, const float* __restrict__ Whh0,
    const float* __restrict__ bih0, const float* __restrict__ bhh0,
    const float* __restrict__ Wih1, const float* __restrict__ Whh1,
    const float* __restrict__ bih1, const float* __restrict__ bhh1,
    const unsigned short* __restrict__ mixed,   // [B*T][H] bf16
    unsigned short* __restrict__ h1,
    unsigned short* __restrict__ h2,
    unsigned short* __restrict__ xgs0,          // [64][8][32][48] bf16
    unsigned short* __restrict__ xgs1,
    unsigned int* __restrict__ flags)           // 4 sets x 64 x 16 u32
{
    __shared__ __align__(16) unsigned short wlds[48*1032];
    __shared__ float sc[3][32][17];
    __shared__ uint32_t hlds[32][8];
    const int tid = threadIdx.x;
    const int lane = tid & 63;
    const int w = tid >> 6;
    const int bid = blockIdx.x;
    const int role = bid >> 6, rb = bid & 63;
    const int j0 = rb * 16;
    const int mh = w & 1, g = w >> 1;
    const int cl = lane & 15, kq = lane >> 4;

    unsigned int* fset[4] = { flags, flags + 1024, flags + 2048, flags + 3072 };

    // stage this role's 48-row weight slice f32 -> bf16 LDS (rotated rows)
    const float* Wsrc = (role == 0) ? Wih0 : (role == 1) ? Whh0
                      : (role == 2) ? Wih1 : Whh1;
    for (int i = tid; i < 48*128; i += 384) {
        const int rr = i >> 7, kc = i & 127;
        const int grow = (rr>>4)*1024 + j0 + (rr&15);
        const float* src = Wsrc + (size_t)grow*1024 + kc*8;
        float4 u = *(const float4*)src, v = *(const float4*)(src+4);
        __align__(16) unsigned short tmp[8] =
            {f2b(u.x),f2b(u.y),f2b(u.z),f2b(u.w),f2b(v.x),f2b(v.y),f2b(v.z),f2b(v.w)};
        const int dst = rr*1032 + ((kc*8 + ((rr&7)<<3)) & 1023);
        *(bf16x8*)&wlds[dst] = *(const bf16x8*)tmp;
    }
    __syncthreads();

    const int wr = g*16 + cl;                       // weight row this lane reads
    const unsigned short* wrowbase = &wlds[wr*1032];
    const int woff0 = kq*8 + ((wr & 7) << 3);       // rotation folded into base

    if ((role & 1) == 0) {
        // ---------------- producer: xg = Wih @ hsrc[t] -------------------
        const unsigned short* hsrc = (role == 0) ? mixed : h1;
        unsigned short* xgs = ((role == 0) ? xgs0 : xgs1) + (size_t)rb*8*32*48;
        const unsigned int* waitin = (role == 2) ? fset[1] : nullptr; // P1 waits R0
        const unsigned int* bp     = (role == 0) ? fset[1] : fset[3]; // consumer R
        unsigned int* myflag = &fset[role][rb*16];

        for (int t = 0; t < SEQT; t++) {
            if (w == 0 && waitin) {
                while (__hip_atomic_load(&waitin[lane*16], __ATOMIC_RELAXED,
                                         __HIP_MEMORY_SCOPE_AGENT) < (unsigned)(t+1)) {}
            }
            if (w == 1 && t >= 8) {
                while (__hip_atomic_load(&bp[lane*16], __ATOMIC_RELAXED,
                                         __HIP_MEMORY_SCOPE_AGENT) < (unsigned)(t-7)) {}
            }
            __syncthreads();

            f32x4 A[4];
#pragma unroll
            for (int i = 0; i < 4; i++) A[i] = (f32x4){0.f,0.f,0.f,0.f};
            const unsigned short* hrow =
                hsrc + ((size_t)(mh*16+cl)*SEQT + t)*HID + kq*8;
            matvec32(hrow, wrowbase, woff0, A);
            f32x4 av = (A[0] + A[1]) + (A[2] + A[3]);
#pragma unroll
            for (int r = 0; r < 4; r++)
                sc[g][mh*16 + kq*4 + r][cl] = av[r];
            __syncthreads();

            if (tid < 192) {
                const int b = tid / 6, c16 = (tid % 6) * 8;
                unsigned short v[8];
#pragma unroll
                for (int k = 0; k < 8; k++) {
                    const int col = c16 + k;
                    v[k] = f2b(sc[col >> 4][b][col & 15]);
                }
                const uint64_t lo = (uint64_t)v[0] | ((uint64_t)v[1]<<16)
                                  | ((uint64_t)v[2]<<32) | ((uint64_t)v[3]<<48);
                const uint64_t hi = (uint64_t)v[4] | ((uint64_t)v[5]<<16)
                                  | ((uint64_t)v[6]<<32) | ((uint64_t)v[7]<<48);
                uint64_t* dst = (uint64_t*)(xgs + (((size_t)(t&7)*32 + b)*48 + c16));
                __hip_atomic_store(dst,   lo, __ATOMIC_RELAXED, __HIP_MEMORY_SCOPE_AGENT);
                __hip_atomic_store(dst+1, hi, __ATOMIC_RELAXED, __HIP_MEMORY_SCOPE_AGENT);
            }
            asm volatile("s_waitcnt vmcnt(0)" ::: "memory");
            __syncthreads();
            if (tid == 0)
                __hip_atomic_store(myflag, (unsigned)(t+1),
                                   __ATOMIC_RELAXED, __HIP_MEMORY_SCOPE_AGENT);
        }
    } else {
        // ---------------- recurrent: h[t] from xgs[t] + Whh@h[t-1] -------
        const unsigned short* xgs = ((role == 1) ? xgs0 : xgs1) + (size_t)rb*8*32*48;
        unsigned short* hdst = (role == 1) ? h1 : h2;
        const float* bih = (role == 1) ? bih0 : bih1;
        const float* bhh = (role == 1) ? bhh0 : bhh1;
        const unsigned int* peers = fset[role];
        const unsigned int* prodf = &fset[role-1][rb*16];
        unsigned int* myflag = &fset[role][rb*16];

        const int fb = tid >> 3;
        const int fj = (tid & 7) * 2;
        float hp0 = 0.f, hp1 = 0.f;
        float br0=0,br1=0,bz0=0,bz1=0,bni0=0,bni1=0,bnh0=0,bnh1=0;
        if (tid < 256) {
            br0 = bih[j0+fj]        + bhh[j0+fj];
            br1 = bih[j0+fj+1]      + bhh[j0+fj+1];
            bz0 = bih[HID+j0+fj]    + bhh[HID+j0+fj];
            bz1 = bih[HID+j0+fj+1]  + bhh[HID+j0+fj+1];
            bni0 = bih[2*HID+j0+fj];   bni1 = bih[2*HID+j0+fj+1];
            bnh0 = bhh[2*HID+j0+fj];   bnh1 = bhh[2*HID+j0+fj+1];
        }

        for (int t = 0; t < SEQT; t++) {
            if (w == 0 && t > 0) {
                while (__hip_atomic_load(&peers[lane*16], __ATOMIC_RELAXED,
                                         __HIP_MEMORY_SCOPE_AGENT) < (unsigned)t) {}
            }
            if (w == 2 && lane == 0) {
                while (__hip_atomic_load(prodf, __ATOMIC_RELAXED,
                                         __HIP_MEMORY_SCOPE_AGENT) < (unsigned)(t+1)) {}
            }
            __syncthreads();

            // xg ring reads: agent-scope atomics (L2-bypass, stale-safe)
            uint32_t xr2=0, xz2=0, xn2=0;
            if (tid < 256) {
                const unsigned short* xp = xgs + ((size_t)(t&7)*32 + fb)*48;
                xr2 = __hip_atomic_load((const unsigned int*)(xp + fj),
                                        __ATOMIC_RELAXED, __HIP_MEMORY_SCOPE_AGENT);
                xz2 = __hip_atomic_load((const unsigned int*)(xp + 16 + fj),
                                        __ATOMIC_RELAXED, __HIP_MEMORY_SCOPE_AGENT);
                xn2 = __hip_atomic_load((const unsigned int*)(xp + 32 + fj),
                                        __ATOMIC_RELAXED, __HIP_MEMORY_SCOPE_AGENT);
            }

            f32x4 A[4];
#pragma unroll
            for (int i = 0; i < 4; i++) A[i] = (f32x4){0.f,0.f,0.f,0.f};
            if (t > 0) {
                const unsigned short* hrow =
                    hdst + ((size_t)(mh*16+cl)*SEQT + (t-1))*HID + kq*8;
                matvec32(hrow, wrowbase, woff0, A);
            }
            f32x4 av = (A[0] + A[1]) + (A[2] + A[3]);
#pragma unroll
            for (int r = 0; r < 4; r++)
                sc[g][mh*16 + kq*4 + r][cl] = av[r];
            __syncthreads();

            if (tid < 256) {
                const float r0 = sigm(b2f((unsigned short)(xr2 & 0xFFFF)) + sc[0][fb][fj]   + br0);
                const float r1 = sigm(b2f((unsigned short)(xr2 >> 16))    + sc[0][fb][fj+1] + br1);
                const float z0 = sigm(b2f((unsigned short)(xz2 & 0xFFFF)) + sc[1][fb][fj]   + bz0);
                const float z1 = sigm(b2f((unsigned short)(xz2 >> 16))    + sc[1][fb][fj+1] + bz1);
                const float n0 = tanhf(b2f((unsigned short)(xn2 & 0xFFFF)) + bni0
                                       + r0*(sc[2][fb][fj]   + bnh0));
                const float n1 = tanhf(b2f((unsigned short)(xn2 >> 16))    + bni1
                                       + r1*(sc[2][fb][fj+1] + bnh1));
                const float h0 = (1.0f - z0)*n0 + z0*hp0;
                const float h1v = (1.0f - z1)*n1 + z1*hp1;
                hp0 = h0; hp1 = h1v;
                hlds[fb][fj >> 1] = (uint32_t)f2b(h0) | ((uint32_t)f2b(h1v) << 16);
            }
            __syncthreads();

            if (w == 5) {
                const int pb = lane >> 1, ph = lane & 1;
                const uint32_t v0 = hlds[pb][ph*4 + 0];
                const uint32_t v1 = hlds[pb][ph*4 + 1];
                const uint32_t v2 = hlds[pb][ph*4 + 2];
                const uint32_t v3 = hlds[pb][ph*4 + 3];
                uint64_t* dst = (uint64_t*)(hdst + ((size_t)pb*SEQT + t)*HID + j0 + ph*8);
                __hip_atomic_store(dst,   (uint64_t)v0 | ((uint64_t)v1 << 32),
                                   __ATOMIC_RELAXED, __HIP_MEMORY_SCOPE_AGENT);
                __hip_atomic_store(dst+1, (uint64_t)v2 | ((uint64_t)v3 << 32),
                                   __ATOMIC_RELAXED, __HIP_MEMORY_SCOPE_AGENT);
                asm volatile("s_waitcnt vmcnt(0)" ::: "memory");
                if (lane == 0)
                    __hip_atomic_store(myflag, (unsigned)(t+1),
                                       __ATOMIC_RELAXED, __HIP_MEMORY_SCOPE_AGENT);
            }
        }
    }
}

// ---------------------------------------------------------------------------
__global__ __launch_bounds__(256) void diag_kernel(float* __restrict__ out,
                                                   int n, float code)
{
    for (int i = blockIdx.x * 256 + threadIdx.x; i < n; i += gridDim.x * 256)
        out[i] = (i == 0) ? code : 0.0f;
}

// ---------------------------------------------------------------------------
extern "C" void kernel_launch(void* const* d_in, const int* in_sizes, int n_in,
                              void* d_out, int out_size, void* d_ws, size_t ws_size,
                              hipStream_t stream)
{
    const float* x      = (const float*)d_in[0];
    const float* ctx    = (const float*)d_in[1];
    const float* W_in   = (const float*)d_in[2];
    const float* b_in   = (const float*)d_in[3];
    const float* Wih0   = (const float*)d_in[4];
    const float* Whh0   = (const float*)d_in[5];
    const float* bih0   = (const float*)d_in[6];
    const float* bhh0   = (const float*)d_in[7];
    const float* Wih1   = (const float*)d_in[8];
    const float* Whh1   = (const float*)d_in[9];
    const float* bih1   = (const float*)d_in[10];
    const float* bhh1   = (const float*)d_in[11];
    const float* W_out  = (const float*)d_in[12];
    const float* b_out  = (const float*)d_in[13];
    const float* W_gate = (const float*)d_in[14];
    const float* b_gate = (const float*)d_in[15];
    float* out = (float*)d_out;

    const size_t MX = (size_t)16384 * 1024 * 2;
    const size_t XS = (size_t)64 * 8 * 32 * 48 * 2;
    const size_t GT = (size_t)32 * 1024 * 4;
    const size_t FL = 16384;
    const size_t need = 3*MX + 2*XS + GT + FL;

    if (ws_size < need) {
        diag_kernel<<<2048, 256, 0, stream>>>(out, out_size, (float)(ws_size >> 20));
        return;
    }

    char* ws = (char*)d_ws;
    unsigned short* mixed = (unsigned short*)ws;
    unsigned short* h1    = (unsigned short*)(ws + MX);
    unsigned short* h2    = (unsigned short*)(ws + 2*MX);
    unsigned short* xgs0  = (unsigned short*)(ws + 3*MX);
    unsigned short* xgs1  = (unsigned short*)(ws + 3*MX + XS);
    float*          gate  = (float*)(ws + 3*MX + 2*XS);
    unsigned int*   flags = (unsigned int*)(ws + 3*MX + 2*XS + GT);

    hipMemsetAsync(flags, 0, FL, stream);
    gate_kernel<<<dim3(4, 32), 256, 0, stream>>>(ctx, W_gate, b_gate, gate);

    // mixed = tanh(x @ W_in^T + b_in + ctx[b]) -> bf16
    mfma_gemm<1, 1, 1><<<dim3(8, 128), 256, 0, stream>>>(
        x, W_in, b_in, ctx, nullptr, mixed, 1024, 1024);

    // 4-stage pipelined GRU section
    gru_pipe<<<256, 384, 0, stream>>>(
        Wih0, Whh0, bih0, bhh0, Wih1, Whh1, bih1, bhh1,
        mixed, h1, h2, xgs0, xgs1, flags);

    // out = (h2 * (1+gate)) @ W_out^T + b_out -> f32
    mfma_gemm<2, 1, 0><<<dim3(8, 128), 256, 0, stream>>>(
        h2, W_out, b_out, nullptr, gate, out, 1024, 1024);
}

// Round 9
// 4631.334 us; speedup vs baseline: 1.0251x; 1.0251x over previous
//
#include <hip/hip_runtime.h>
#include <cstdint>
#include <cstddef>

#define SEQT  512
#define HID   1024
#define G3    3072

typedef __attribute__((ext_vector_type(8))) short bf16x8;
typedef __attribute__((ext_vector_type(8))) unsigned short u16x8;
typedef __attribute__((ext_vector_type(4))) float f32x4;

__device__ __forceinline__ float sigm(float x){ return 1.0f/(1.0f+expf(-x)); }
__device__ __forceinline__ float b2f(unsigned short s){ return __uint_as_float(((uint32_t)s)<<16); }
__device__ __forceinline__ unsigned short f2b(float f){
    uint32_t u=__float_as_uint(f);
    return (unsigned short)((u + 0x7FFFu + ((u>>16)&1u))>>16);
}

// ---------------------------------------------------------------------------
// MFMA GEMM (proven since R3). ASRC: 1=f32 reg-staged, 2=bf16 + (1+gate) fuse.
// BSRC: 1=f32 reg-staged. MODE: 0=f32+bias, 1=bf16 tanh(+bias+ctx).
// ---------------------------------------------------------------------------
template<int ASRC, int BSRC, int MODE>
__global__ __launch_bounds__(256) void mfma_gemm(
    const void* __restrict__ Av, const void* __restrict__ Bv,
    const float* __restrict__ bias, const float* __restrict__ ctx,
    const float* __restrict__ gate, void* __restrict__ Cv,
    int N, int K)
{
    __shared__ __align__(16) unsigned short As[128*64];
    __shared__ __align__(16) unsigned short Bs[128*64];
    const int tid = threadIdx.x;
    const int lane = tid & 63;
    const int w = tid >> 6;
    const int wm = w & 1, wn = w >> 1;
    const int m0 = blockIdx.y * 128, n0 = blockIdx.x * 128;

    f32x4 acc[4][4];
#pragma unroll
    for (int i = 0; i < 4; i++)
#pragma unroll
        for (int j = 0; j < 4; j++) acc[i][j] = (f32x4){0.f,0.f,0.f,0.f};

    for (int kt = 0; kt < K; kt += 64) {
        __syncthreads();
        if (ASRC == 1) {
            const float* Af = (const float*)Av;
#pragma unroll
            for (int p = 0; p < 4; p++) {
                const int q = p*256 + tid, row = q>>3, kc = q&7;
                const float* src = Af + (size_t)(m0+row)*K + kt + kc*8;
                float4 u = *(const float4*)src, v = *(const float4*)(src+4);
                __align__(16) unsigned short tmp[8] =
                    {f2b(u.x),f2b(u.y),f2b(u.z),f2b(u.w),f2b(v.x),f2b(v.y),f2b(v.z),f2b(v.w)};
                *(bf16x8*)&As[row*64 + kc*8] = *(const bf16x8*)tmp;
            }
        } else {
            const unsigned short* Ab = (const unsigned short*)Av;
#pragma unroll
            for (int p = 0; p < 4; p++) {
                const int q = p*256 + tid, row = q>>3, kc = q&7;
                const int b = (m0+row) >> 9;
                u16x8 hv = *(const u16x8*)(Ab + (size_t)(m0+row)*K + kt + kc*8);
                const float* gp = gate + (size_t)b*HID + kt + kc*8;
                float4 g0 = *(const float4*)gp, g1 = *(const float4*)(gp+4);
                const float gg[8] = {g0.x,g0.y,g0.z,g0.w,g1.x,g1.y,g1.z,g1.w};
                __align__(16) unsigned short tmp[8];
#pragma unroll
                for (int e = 0; e < 8; e++)
                    tmp[e] = f2b(b2f(hv[e]) * (1.0f + gg[e]));
                *(bf16x8*)&As[row*64 + kc*8] = *(const bf16x8*)tmp;
            }
        }
        {
            const float* Bf = (const float*)Bv;
#pragma unroll
            for (int p = 0; p < 4; p++) {
                const int q = p*256 + tid, row = q>>3, kc = q&7;
                const float* src = Bf + (size_t)(n0+row)*K + kt + kc*8;
                float4 u = *(const float4*)src, v = *(const float4*)(src+4);
                __align__(16) unsigned short tmp[8] =
                    {f2b(u.x),f2b(u.y),f2b(u.z),f2b(u.w),f2b(v.x),f2b(v.y),f2b(v.z),f2b(v.w)};
                *(bf16x8*)&Bs[row*64 + kc*8] = *(const bf16x8*)tmp;
            }
        }
        __syncthreads();
#pragma unroll
        for (int kg = 0; kg < 2; kg++) {
            bf16x8 af[4], bfr[4];
#pragma unroll
            for (int mi = 0; mi < 4; mi++)
                af[mi] = *(const bf16x8*)&As[(wm*64+mi*16+(lane&15))*64 + kg*32 + (lane>>4)*8];
#pragma unroll
            for (int ni = 0; ni < 4; ni++)
                bfr[ni] = *(const bf16x8*)&Bs[(wn*64+ni*16+(lane&15))*64 + kg*32 + (lane>>4)*8];
#pragma unroll
            for (int mi = 0; mi < 4; mi++)
#pragma unroll
                for (int ni = 0; ni < 4; ni++)
                    acc[mi][ni] = __builtin_amdgcn_mfma_f32_16x16x32_bf16(
                        af[mi], bfr[ni], acc[mi][ni], 0, 0, 0);
        }
    }

    const int cl = lane & 15, rg = lane >> 4;
    const int bct = m0 >> 9;
#pragma unroll
    for (int mi = 0; mi < 4; mi++) {
        const int rowb = m0 + wm*64 + mi*16 + rg*4;
#pragma unroll
        for (int ni = 0; ni < 4; ni++) {
            const int col = n0 + wn*64 + ni*16 + cl;
            const float bv = bias[col];
            const float cv = (MODE==1) ? ctx[(size_t)bct*HID + col] : 0.0f;
#pragma unroll
            for (int r = 0; r < 4; r++) {
                float val = acc[mi][ni][r] + bv;
                if (MODE==1) val = tanhf(val + cv);
                const size_t off = (size_t)(rowb+r)*N + col;
                if (MODE==0) ((float*)Cv)[off] = val;
                else ((unsigned short*)Cv)[off] = f2b(val);
            }
        }
    }
}

// ---------------------------------------------------------------------------
__global__ __launch_bounds__(256) void gate_kernel(
    const float* __restrict__ ctx, const float* __restrict__ Wg,
    const float* __restrict__ bg, float* __restrict__ gate)
{
    const int j = blockIdx.x * 256 + threadIdx.x;
    const int b = blockIdx.y;
    const float4* cp = (const float4*)(ctx + (size_t)b * HID);
    const float4* wp = (const float4*)(Wg + (size_t)j * HID);
    float acc = 0.0f;
#pragma unroll 4
    for (int k = 0; k < HID / 4; k++) {
        float4 c = cp[k], w = wp[k];
        acc += c.x * w.x + c.y * w.y + c.z * w.z + c.w * w.w;
    }
    gate[(size_t)b * HID + j] = sigm(acc + bg[j]);
}

// ---------------------------------------------------------------------------
// 4-stage pipelined GRU section (structure proven R7). This round:
//  * matvec: 32 pre-issued global h-loads pinned by sched_barrier(0) before
//    the 32 MFMAs -> deep VMEM pipeline (VGPR rises by design).
//  * wlds row-rotation swizzle: row k-layout rotated by (row&7)*8 shorts
//    (mod 1024) on write AND read -> uniform bank phases on ds_read_b128.
// ---------------------------------------------------------------------------
__device__ __forceinline__ void matvec32(const unsigned short* __restrict__ hrow,
                                         const unsigned short* __restrict__ wrowbase,
                                         int woff0, f32x4 (&A)[4])
{
    bf16x8 hb[32];
#pragma unroll
    for (int kg = 0; kg < 32; kg++)
        hb[kg] = *(const bf16x8*)(hrow + (size_t)kg*32);
    __builtin_amdgcn_sched_barrier(0);
#pragma unroll
    for (int kg = 0; kg < 32; kg++) {
        bf16x8 wv = *(const bf16x8*)(wrowbase + ((woff0 + kg*32) & 1023));
        A[kg & 3] = __builtin_amdgcn_mfma_f32_16x16x32_bf16(hb[kg], wv, A[kg & 3], 0,0,0);
    }
}

__global__ __launch_bounds__(384, 1) void gru_pipe(
    const float* __restrict__ Wih0, const float* __restrict__ Whh0,
    const float* __restrict__ bih0, const float* __restrict__ bhh0,
    const float* __restrict__ Wih1, const float* __restrict__ Whh1,
    const float* __restrict__ bih1, const float* __restrict__ bhh1,
    const unsigned short* __restrict__ mixed,   // [B*T][H] bf16
    unsigned short* __restrict__ h1,
    unsigned short* __restrict__ h2,
    unsigned short* __restrict__ xgs0,          // [64][8][32][48] bf16
    unsigned short* __restrict__ xgs1,
    unsigned int* __restrict__ flags)           // 4 sets x 64 x 16 u32
{
    __shared__ __align__(16) unsigned short wlds[48*1032];
    __shared__ float sc[3][32][17];
    __shared__ uint32_t hlds[32][8];
    const int tid = threadIdx.x;
    const int lane = tid & 63;
    const int w = tid >> 6;
    const int bid = blockIdx.x;
    const int role = bid >> 6, rb = bid & 63;
    const int j0 = rb * 16;
    const int mh = w & 1, g = w >> 1;
    const int cl = lane & 15, kq = lane >> 4;

    unsigned int* fset[4] = { flags, flags + 1024, flags + 2048, flags + 3072 };

    // stage this role's 48-row weight slice f32 -> bf16 LDS (rotated rows)
    const float* Wsrc = (role == 0) ? Wih0 : (role == 1) ? Whh0
                      : (role == 2) ? Wih1 : Whh1;
    for (int i = tid; i < 48*128; i += 384) {
        const int rr = i >> 7, kc = i & 127;
        const int grow = (rr>>4)*1024 + j0 + (rr&15);
        const float* src = Wsrc + (size_t)grow*1024 + kc*8;
        float4 u = *(const float4*)src, v = *(const float4*)(src+4);
        __align__(16) unsigned short tmp[8] =
            {f2b(u.x),f2b(u.y),f2b(u.z),f2b(u.w),f2b(v.x),f2b(v.y),f2b(v.z),f2b(v.w)};
        const int dst = rr*1032 + ((kc*8 + ((rr&7)<<3)) & 1023);
        *(bf16x8*)&wlds[dst] = *(const bf16x8*)tmp;
    }
    __syncthreads();

    const int wr = g*16 + cl;                       // weight row this lane reads
    const unsigned short* wrowbase = &wlds[wr*1032];
    const int woff0 = kq*8 + ((wr & 7) << 3);       // rotation folded into base

    if ((role & 1) == 0) {
        // ---------------- producer: xg = Wih @ hsrc[t] -------------------
        const unsigned short* hsrc = (role == 0) ? mixed : h1;
        unsigned short* xgs = ((role == 0) ? xgs0 : xgs1) + (size_t)rb*8*32*48;
        const unsigned int* waitin = (role == 2) ? fset[1] : nullptr; // P1 waits R0
        const unsigned int* bp     = (role == 0) ? fset[1] : fset[3]; // consumer R
        unsigned int* myflag = &fset[role][rb*16];

        for (int t = 0; t < SEQT; t++) {
            if (w == 0 && waitin) {
                while (__hip_atomic_load(&waitin[lane*16], __ATOMIC_RELAXED,
                                         __HIP_MEMORY_SCOPE_AGENT) < (unsigned)(t+1)) {}
            }
            if (w == 1 && t >= 8) {
                while (__hip_atomic_load(&bp[lane*16], __ATOMIC_RELAXED,
                                         __HIP_MEMORY_SCOPE_AGENT) < (unsigned)(t-7)) {}
            }
            __syncthreads();

            f32x4 A[4];
#pragma unroll
            for (int i = 0; i < 4; i++) A[i] = (f32x4){0.f,0.f,0.f,0.f};
            const unsigned short* hrow =
                hsrc + ((size_t)(mh*16+cl)*SEQT + t)*HID + kq*8;
            matvec32(hrow, wrowbase, woff0, A);
            f32x4 av = (A[0] + A[1]) + (A[2] + A[3]);
#pragma unroll
            for (int r = 0; r < 4; r++)
                sc[g][mh*16 + kq*4 + r][cl] = av[r];
            __syncthreads();

            if (tid < 192) {
                const int b = tid / 6, c16 = (tid % 6) * 8;
                unsigned short v[8];
#pragma unroll
                for (int k = 0; k < 8; k++) {
                    const int col = c16 + k;
                    v[k] = f2b(sc[col >> 4][b][col & 15]);
                }
                const uint64_t lo = (uint64_t)v[0] | ((uint64_t)v[1]<<16)
                                  | ((uint64_t)v[2]<<32) | ((uint64_t)v[3]<<48);
                const uint64_t hi = (uint64_t)v[4] | ((uint64_t)v[5]<<16)
                                  | ((uint64_t)v[6]<<32) | ((uint64_t)v[7]<<48);
                uint64_t* dst = (uint64_t*)(xgs + (((size_t)(t&7)*32 + b)*48 + c16));
                __hip_atomic_store(dst,   lo, __ATOMIC_RELAXED, __HIP_MEMORY_SCOPE_AGENT);
                __hip_atomic_store(dst+1, hi, __ATOMIC_RELAXED, __HIP_MEMORY_SCOPE_AGENT);
            }
            asm volatile("s_waitcnt vmcnt(0)" ::: "memory");
            __syncthreads();
            if (tid == 0)
                __hip_atomic_store(myflag, (unsigned)(t+1),
                                   __ATOMIC_RELAXED, __HIP_MEMORY_SCOPE_AGENT);
        }
    } else {
        // ---------------- recurrent: h[t] from xgs[t] + Whh@h[t-1] -------
        const unsigned short* xgs = ((role == 1) ? xgs0 : xgs1) + (size_t)rb*8*32*48;
        unsigned short* hdst = (role == 1) ? h1 : h2;
        const float* bih = (role == 1) ? bih0 : bih1;
        const float* bhh = (role == 1) ? bhh0 : bhh1;
        const unsigned int* peers = fset[role];
        const unsigned int* prodf = &fset[role-1][rb*16];
        unsigned int* myflag = &fset[role][rb*16];

        const int fb = tid >> 3;
        const int fj = (tid & 7) * 2;
        float hp0 = 0.f, hp1 = 0.f;
        float br0=0,br1=0,bz0=0,bz1=0,bni0=0,bni1=0,bnh0=0,bnh1=0;
        if (tid < 256) {
            br0 = bih[j0+fj]        + bhh[j0+fj];
            br1 = bih[j0+fj+1]      + bhh[j0+fj+1];
            bz0 = bih[HID+j0+fj]    + bhh[HID+j0+fj];
            bz1 = bih[HID+j0+fj+1]  + bhh[HID+j0+fj+1];
            bni0 = bih[2*HID+j0+fj];   bni1 = bih[2*HID+j0+fj+1];
            bnh0 = bhh[2*HID+j0+fj];   bnh1 = bhh[2*HID+j0+fj+1];
        }

        for (int t = 0; t < SEQT; t++) {
            if (w == 0 && t > 0) {
                while (__hip_atomic_load(&peers[lane*16], __ATOMIC_RELAXED,
                                         __HIP_MEMORY_SCOPE_AGENT) < (unsigned)t) {}
            }
            if (w == 2 && lane == 0) {
                while (__hip_atomic_load(prodf, __ATOMIC_RELAXED,
                                         __HIP_MEMORY_SCOPE_AGENT) < (unsigned)(t+1)) {}
            }
            __syncthreads();

            // xg ring reads: agent-scope atomics (L2-bypass, stale-safe)
            uint32_t xr2=0, xz2=0, xn2=0;
            if (tid < 256) {
                const unsigned short* xp = xgs + ((size_t)(t&7)*32 + fb)*48;
                xr2 = __hip_atomic_load((const unsigned int*)(xp + fj),
                                        __ATOMIC_RELAXED, __HIP_MEMORY_SCOPE_AGENT);
                xz2 = __hip_atomic_load((const unsigned int*)(xp + 16 + fj),
                                        __ATOMIC_RELAXED, __HIP_MEMORY_SCOPE_AGENT);
                xn2 = __hip_atomic_load((const unsigned int*)(xp + 32 + fj),
                                        __ATOMIC_RELAXED, __HIP_MEMORY_SCOPE_AGENT);
            }

            f32x4 A[4];
#pragma unroll
            for (int i = 0; i < 4; i++) A[i] = (f32x4){0.f,0.f,0.f,0.f};
            if (t > 0) {
                const unsigned short* hrow =
                    hdst + ((size_t)(mh*16+cl)*SEQT + (t-1))*HID + kq*8;
                matvec32(hrow, wrowbase, woff0, A);
            }
            f32x4 av = (A[0] + A[1]) + (A[2] + A[3]);
#pragma unroll
            for (int r = 0; r < 4; r++)
                sc[g][mh*16 + kq*4 + r][cl] = av[r];
            __syncthreads();

            if (tid < 256) {
                const float r0 = sigm(b2f((unsigned short)(xr2 & 0xFFFF)) + sc[0][fb][fj]   + br0);
                const float r1 = sigm(b2f((unsigned short)(xr2 >> 16))    + sc[0][fb][fj+1] + br1);
                const float z0 = sigm(b2f((unsigned short)(xz2 & 0xFFFF)) + sc[1][fb][fj]   + bz0);
                const float z1 = sigm(b2f((unsigned short)(xz2 >> 16))    + sc[1][fb][fj+1] + bz1);
                const float n0 = tanhf(b2f((unsigned short)(xn2 & 0xFFFF)) + bni0
                                       + r0*(sc[2][fb][fj]   + bnh0));
                const float n1 = tanhf(b2f((unsigned short)(xn2 >> 16))    + bni1
                                       + r1*(sc[2][fb][fj+1] + bnh1));
                const float h0 = (1.0f - z0)*n0 + z0*hp0;
                const float h1v = (1.0f - z1)*n1 + z1*hp1;
                hp0 = h0; hp1 = h1v;
                hlds[fb][fj >> 1] = (uint32_t)f2b(h0) | ((uint32_t)f2b(h1v) << 16);
            }
            __syncthreads();

            if (w == 5) {
                const int pb = lane >> 1, ph = lane & 1;
                const uint32_t v0 = hlds[pb][ph*4 + 0];
                const uint32_t v1 = hlds[pb][ph*4 + 1];
                const uint32_t v2 = hlds[pb][ph*4 + 2];
                const uint32_t v3 = hlds[pb][ph*4 + 3];
                uint64_t* dst = (uint64_t*)(hdst + ((size_t)pb*SEQT + t)*HID + j0 + ph*8);
                __hip_atomic_store(dst,   (uint64_t)v0 | ((uint64_t)v1 << 32),
                                   __ATOMIC_RELAXED, __HIP_MEMORY_SCOPE_AGENT);
                __hip_atomic_store(dst+1, (uint64_t)v2 | ((uint64_t)v3 << 32),
                                   __ATOMIC_RELAXED, __HIP_MEMORY_SCOPE_AGENT);
                asm volatile("s_waitcnt vmcnt(0)" ::: "memory");
                if (lane == 0)
                    __hip_atomic_store(myflag, (unsigned)(t+1),
                                       __ATOMIC_RELAXED, __HIP_MEMORY_SCOPE_AGENT);
            }
        }
    }
}

// ---------------------------------------------------------------------------
__global__ __launch_bounds__(256) void diag_kernel(float* __restrict__ out,
                                                   int n, float code)
{
    for (int i = blockIdx.x * 256 + threadIdx.x; i < n; i += gridDim.x * 256)
        out[i] = (i == 0) ? code : 0.0f;
}

// ---------------------------------------------------------------------------
extern "C" void kernel_launch(void* const* d_in, const int* in_sizes, int n_in,
                              void* d_out, int out_size, void* d_ws, size_t ws_size,
                              hipStream_t stream)
{
    const float* x      = (const float*)d_in[0];
    const float* ctx    = (const float*)d_in[1];
    const float* W_in   = (const float*)d_in[2];
    const float* b_in   = (const float*)d_in[3];
    const float* Wih0   = (const float*)d_in[4];
    const float* Whh0   = (const float*)d_in[5];
    const float* bih0   = (const float*)d_in[6];
    const float* bhh0   = (const float*)d_in[7];
    const float* Wih1   = (const float*)d_in[8];
    const float* Whh1   = (const float*)d_in[9];
    const float* bih1   = (const float*)d_in[10];
    const float* bhh1   = (const float*)d_in[11];
    const float* W_out  = (const float*)d_in[12];
    const float* b_out  = (const float*)d_in[13];
    const float* W_gate = (const float*)d_in[14];
    const float* b_gate = (const float*)d_in[15];
    float* out = (float*)d_out;

    const size_t MX = (size_t)16384 * 1024 * 2;
    const size_t XS = (size_t)64 * 8 * 32 * 48 * 2;
    const size_t GT = (size_t)32 * 1024 * 4;
    const size_t FL = 16384;
    const size_t need = 3*MX + 2*XS + GT + FL;

    if (ws_size < need) {
        diag_kernel<<<2048, 256, 0, stream>>>(out, out_size, (float)(ws_size >> 20));
        return;
    }

    char* ws = (char*)d_ws;
    unsigned short* mixed = (unsigned short*)ws;
    unsigned short* h1    = (unsigned short*)(ws + MX);
    unsigned short* h2    = (unsigned short*)(ws + 2*MX);
    unsigned short* xgs0  = (unsigned short*)(ws + 3*MX);
    unsigned short* xgs1  = (unsigned short*)(ws + 3*MX + XS);
    float*          gate  = (float*)(ws + 3*MX + 2*XS);
    unsigned int*   flags = (unsigned int*)(ws + 3*MX + 2*XS + GT);

    hipMemsetAsync(flags, 0, FL, stream);
    gate_kernel<<<dim3(4, 32), 256, 0, stream>>>(ctx, W_gate, b_gate, gate);

    // mixed = tanh(x @ W_in^T + b_in + ctx[b]) -> bf16
    mfma_gemm<1, 1, 1><<<dim3(8, 128), 256, 0, stream>>>(
        x, W_in, b_in, ctx, nullptr, mixed, 1024, 1024);

    // 4-stage pipelined GRU section
    gru_pipe<<<256, 384, 0, stream>>>(
        Wih0, Whh0, bih0, bhh0, Wih1, Whh1, bih1, bhh1,
        mixed, h1, h2, xgs0, xgs1, flags);

    // out = (h2 * (1+gate)) @ W_out^T + b_out -> f32
    mfma_gemm<2, 1, 0><<<dim3(8, 128), 256, 0, stream>>>(
        h2, W_out, b_out, nullptr, gate, out, 1024, 1024);
}